// Round 1
// baseline (2542.488 us; speedup 1.0000x reference)
//
#include <hip/hip_runtime.h>
#include <math.h>

#define RB 32      // rows per block
#define NT 256     // threads per block

// ws layout (floats):
//  T0 @ 0      : [64][256]   T0[s][n] = W0[n][1+s]   (fwd layer0 B)
//  T1 @ 16384  : [256][256]  T1[s][n] = W1[n][1+s]   (fwd layer1 B)
//  T2 @ 81920  : [256][64]   T2[s][n] = W2[n][1+s]   (fwd layer2 B)
//  V2 @ 98304  : [64][256]   V2[s][n] = W2[s][1+n]   (bwd g2 B)
//  V1 @ 114688 : [256][256]  V1[s][n] = W1[s][1+n]   (bwd g1 B)
//  V0 @ 180224 : [256][64]   V0[s][n] = W0[s][1+n]   (bwd g0 B)
#define WS_FLOATS 196608

__device__ __forceinline__ float softplus_f(float x) {
    return fmaxf(x, 0.0f) + log1pf(__expf(-fabsf(x)));
}

__global__ void prep_kernel(const float* __restrict__ W0,
                            const float* __restrict__ W1,
                            const float* __restrict__ W2,
                            float* __restrict__ ws)
{
    int i = blockIdx.x * blockDim.x + threadIdx.x;
    if (i < 16384) {                            // T0
        int s = i >> 8, n = i & 255;
        ws[i] = W0[n * 65 + 1 + s];
    } else if (i < 81920) {                     // T1
        int j = i - 16384; int s = j >> 8, n = j & 255;
        ws[i] = W1[n * 257 + 1 + s];
    } else if (i < 98304) {                     // T2
        int j = i - 81920; int s = j >> 6, n = j & 63;
        ws[i] = W2[n * 257 + 1 + s];
    } else if (i < 114688) {                    // V2
        int j = i - 98304; int s = j >> 8, n = j & 255;
        ws[i] = W2[s * 257 + 1 + n];
    } else if (i < 180224) {                    // V1
        int j = i - 114688; int s = j >> 8, n = j & 255;
        ws[i] = W1[s * 257 + 1 + n];
    } else if (i < WS_FLOATS) {                 // V0
        int j = i - 180224; int s = j >> 6, n = j & 63;
        ws[i] = W0[s * 65 + 1 + n];
    }
}

template <bool WS>
__global__ __launch_bounds__(NT, 2)
void ode_kernel(const float* __restrict__ tptr,
                const float* __restrict__ y,
                const float* __restrict__ e,
                const float* __restrict__ W0, const float* __restrict__ b0,
                const float* __restrict__ W1, const float* __restrict__ b1,
                const float* __restrict__ W2, const float* __restrict__ b2,
                const float* __restrict__ ws,
                float* __restrict__ out)
{
    // LDS: 32*257*4*2 + 32*68*4 = 74496 B -> 2 blocks/CU
    __shared__ float H0[RB * 257];   // h0, later p0
    __shared__ float H1[RB * 257];   // h1, later p1
    __shared__ float ZE[RB * 68];    // z, later e (stride 68 keeps f4 alignment)

    const int tid = threadIdx.x;
    const int rowbase = blockIdx.x * RB;
    const float tval = tptr[0];

    const float* T0 = ws;
    const float* T1 = ws + 16384;
    const float* T2 = ws + 81920;
    const float* V2 = ws + 98304;
    const float* V1 = ws + 114688;
    const float* V0 = ws + 180224;

    const int cg  = tid & 31, rg  = tid >> 5;   // 256-col gemms: 4 rows x 8 cols/thread
    const int cg2 = tid & 15, rg2 = tid >> 4;   // 64-col gemms:  2 rows x 4 cols/thread

    // ---- stage z = y[:, :64] ----
    {
        const int d = tid & 63, r0 = tid >> 6;
        for (int r = r0; r < RB; r += NT / 64)
            ZE[r * 68 + d] = y[(rowbase + r) * 65 + d];
    }
    __syncthreads();

    float acc[4][8];
    float acc2[2][4];

    // ================= layer 0: h0 = softplus(z @ W0[:,1:]^T + t*W0[:,0] + b0)
    #pragma unroll
    for (int i = 0; i < 4; ++i) {
        #pragma unroll
        for (int j = 0; j < 8; ++j) acc[i][j] = 0.0f;
    }
    #pragma unroll 4
    for (int s = 0; s < 64; ++s) {
        float b[8];
        if (WS) {
            float4 u0 = *(const float4*)(T0 + s * 256 + cg * 8);
            float4 u1 = *(const float4*)(T0 + s * 256 + cg * 8 + 4);
            b[0] = u0.x; b[1] = u0.y; b[2] = u0.z; b[3] = u0.w;
            b[4] = u1.x; b[5] = u1.y; b[6] = u1.z; b[7] = u1.w;
        } else {
            #pragma unroll
            for (int j = 0; j < 8; ++j) b[j] = W0[(cg * 8 + j) * 65 + 1 + s];
        }
        float a[4];
        #pragma unroll
        for (int i = 0; i < 4; ++i) a[i] = ZE[(rg * 4 + i) * 68 + s];
        #pragma unroll
        for (int i = 0; i < 4; ++i) {
            #pragma unroll
            for (int j = 0; j < 8; ++j) acc[i][j] = fmaf(a[i], b[j], acc[i][j]);
        }
    }
    #pragma unroll
    for (int i = 0; i < 4; ++i) {
        const int r = rg * 4 + i;
        #pragma unroll
        for (int j = 0; j < 8; ++j) {
            const int n = cg * 8 + j;
            H0[r * 257 + n] = softplus_f(acc[i][j] + tval * W0[n * 65] + b0[n]);
        }
    }
    __syncthreads();

    // ---- stage e (overwrites z; consumed only after the next barrier) ----
    for (int idx = tid; idx < RB * 16; idx += NT) {
        const int r = idx >> 4, c = idx & 15;
        *(float4*)(&ZE[r * 68 + c * 4]) = *(const float4*)(e + (rowbase + r) * 64 + c * 4);
    }

    // ================= layer 1: h1 = softplus(h0 @ W1[:,1:]^T + t*W1[:,0] + b1)
    #pragma unroll
    for (int i = 0; i < 4; ++i) {
        #pragma unroll
        for (int j = 0; j < 8; ++j) acc[i][j] = 0.0f;
    }
    #pragma unroll 2
    for (int s = 0; s < 256; ++s) {
        float b[8];
        if (WS) {
            float4 u0 = *(const float4*)(T1 + s * 256 + cg * 8);
            float4 u1 = *(const float4*)(T1 + s * 256 + cg * 8 + 4);
            b[0] = u0.x; b[1] = u0.y; b[2] = u0.z; b[3] = u0.w;
            b[4] = u1.x; b[5] = u1.y; b[6] = u1.z; b[7] = u1.w;
        } else {
            #pragma unroll
            for (int j = 0; j < 8; ++j) b[j] = W1[(cg * 8 + j) * 257 + 1 + s];
        }
        float a[4];
        #pragma unroll
        for (int i = 0; i < 4; ++i) a[i] = H0[(rg * 4 + i) * 257 + s];
        #pragma unroll
        for (int i = 0; i < 4; ++i) {
            #pragma unroll
            for (int j = 0; j < 8; ++j) acc[i][j] = fmaf(a[i], b[j], acc[i][j]);
        }
    }
    #pragma unroll
    for (int i = 0; i < 4; ++i) {
        const int r = rg * 4 + i;
        #pragma unroll
        for (int j = 0; j < 8; ++j) {
            const int n = cg * 8 + j;
            H1[r * 257 + n] = softplus_f(acc[i][j] + tval * W1[n * 257] + b1[n]);
        }
    }
    __syncthreads();

    // ================= layer 2: dx = h1 @ W2[:,1:]^T + t*W2[:,0] + b2  -> out[:, :64]
    #pragma unroll
    for (int i = 0; i < 2; ++i) {
        #pragma unroll
        for (int j = 0; j < 4; ++j) acc2[i][j] = 0.0f;
    }
    #pragma unroll 2
    for (int s = 0; s < 256; ++s) {
        float b[4];
        if (WS) {
            float4 u = *(const float4*)(T2 + s * 64 + cg2 * 4);
            b[0] = u.x; b[1] = u.y; b[2] = u.z; b[3] = u.w;
        } else {
            #pragma unroll
            for (int j = 0; j < 4; ++j) b[j] = W2[(cg2 * 4 + j) * 257 + 1 + s];
        }
        float a[2];
        #pragma unroll
        for (int i = 0; i < 2; ++i) a[i] = H1[(rg2 * 2 + i) * 257 + s];
        #pragma unroll
        for (int i = 0; i < 2; ++i) {
            #pragma unroll
            for (int j = 0; j < 4; ++j) acc2[i][j] = fmaf(a[i], b[j], acc2[i][j]);
        }
    }
    #pragma unroll
    for (int i = 0; i < 2; ++i) {
        const int r = rg2 * 2 + i;
        #pragma unroll
        for (int j = 0; j < 4; ++j) {
            const int n = cg2 * 4 + j;
            out[(rowbase + r) * 65 + n] = acc2[i][j] + tval * W2[n * 257] + b2[n];
        }
    }
    __syncthreads();   // all h1 reads done before p1 overwrites H1

    // ================= g2 = e @ W2[:,1:], p1 = g2 * sigmoid(a1) -> H1
    // sigmoid(a) = 1 - exp(-softplus(a)) = 1 - exp(-h)
    #pragma unroll
    for (int i = 0; i < 4; ++i) {
        #pragma unroll
        for (int j = 0; j < 8; ++j) acc[i][j] = 0.0f;
    }
    #pragma unroll 4
    for (int s = 0; s < 64; ++s) {
        float b[8];
        if (WS) {
            float4 u0 = *(const float4*)(V2 + s * 256 + cg * 8);
            float4 u1 = *(const float4*)(V2 + s * 256 + cg * 8 + 4);
            b[0] = u0.x; b[1] = u0.y; b[2] = u0.z; b[3] = u0.w;
            b[4] = u1.x; b[5] = u1.y; b[6] = u1.z; b[7] = u1.w;
        } else {
            #pragma unroll
            for (int j = 0; j < 8; ++j) b[j] = W2[s * 257 + 1 + cg * 8 + j];
        }
        float a[4];
        #pragma unroll
        for (int i = 0; i < 4; ++i) a[i] = ZE[(rg * 4 + i) * 68 + s];
        #pragma unroll
        for (int i = 0; i < 4; ++i) {
            #pragma unroll
            for (int j = 0; j < 8; ++j) acc[i][j] = fmaf(a[i], b[j], acc[i][j]);
        }
    }
    #pragma unroll
    for (int i = 0; i < 4; ++i) {
        const int r = rg * 4 + i;
        #pragma unroll
        for (int j = 0; j < 8; ++j) {
            const int n = cg * 8 + j;
            const float h = H1[r * 257 + n];
            H1[r * 257 + n] = acc[i][j] * (1.0f - __expf(-h));
        }
    }
    __syncthreads();

    // ================= g1 = p1 @ W1[:,1:], p0 = g1 * sigmoid(a0) -> H0
    #pragma unroll
    for (int i = 0; i < 4; ++i) {
        #pragma unroll
        for (int j = 0; j < 8; ++j) acc[i][j] = 0.0f;
    }
    #pragma unroll 2
    for (int s = 0; s < 256; ++s) {
        float b[8];
        if (WS) {
            float4 u0 = *(const float4*)(V1 + s * 256 + cg * 8);
            float4 u1 = *(const float4*)(V1 + s * 256 + cg * 8 + 4);
            b[0] = u0.x; b[1] = u0.y; b[2] = u0.z; b[3] = u0.w;
            b[4] = u1.x; b[5] = u1.y; b[6] = u1.z; b[7] = u1.w;
        } else {
            #pragma unroll
            for (int j = 0; j < 8; ++j) b[j] = W1[s * 257 + 1 + cg * 8 + j];
        }
        float a[4];
        #pragma unroll
        for (int i = 0; i < 4; ++i) a[i] = H1[(rg * 4 + i) * 257 + s];
        #pragma unroll
        for (int i = 0; i < 4; ++i) {
            #pragma unroll
            for (int j = 0; j < 8; ++j) acc[i][j] = fmaf(a[i], b[j], acc[i][j]);
        }
    }
    #pragma unroll
    for (int i = 0; i < 4; ++i) {
        const int r = rg * 4 + i;
        #pragma unroll
        for (int j = 0; j < 8; ++j) {
            const int n = cg * 8 + j;
            const float h = H0[r * 257 + n];
            H0[r * 257 + n] = acc[i][j] * (1.0f - __expf(-h));
        }
    }
    __syncthreads();

    // ================= g0 = p0 @ W0[:,1:]; div = sum(g0*e); out[:,64] = -div
    #pragma unroll
    for (int i = 0; i < 2; ++i) {
        #pragma unroll
        for (int j = 0; j < 4; ++j) acc2[i][j] = 0.0f;
    }
    #pragma unroll 2
    for (int s = 0; s < 256; ++s) {
        float b[4];
        if (WS) {
            float4 u = *(const float4*)(V0 + s * 64 + cg2 * 4);
            b[0] = u.x; b[1] = u.y; b[2] = u.z; b[3] = u.w;
        } else {
            #pragma unroll
            for (int j = 0; j < 4; ++j) b[j] = W0[s * 65 + 1 + cg2 * 4 + j];
        }
        float a[2];
        #pragma unroll
        for (int i = 0; i < 2; ++i) a[i] = H0[(rg2 * 2 + i) * 257 + s];
        #pragma unroll
        for (int i = 0; i < 2; ++i) {
            #pragma unroll
            for (int j = 0; j < 4; ++j) acc2[i][j] = fmaf(a[i], b[j], acc2[i][j]);
        }
    }
    float pA = 0.0f, pB = 0.0f;
    #pragma unroll
    for (int j = 0; j < 4; ++j) {
        const int n = cg2 * 4 + j;
        pA = fmaf(acc2[0][j], ZE[(rg2 * 2 + 0) * 68 + n], pA);
        pB = fmaf(acc2[1][j], ZE[(rg2 * 2 + 1) * 68 + n], pB);
    }
    #pragma unroll
    for (int off = 8; off > 0; off >>= 1) {
        pA += __shfl_down(pA, off, 16);
        pB += __shfl_down(pB, off, 16);
    }
    if (cg2 == 0) {
        out[(rowbase + rg2 * 2 + 0) * 65 + 64] = -pA;
        out[(rowbase + rg2 * 2 + 1) * 65 + 64] = -pB;
    }
}

extern "C" void kernel_launch(void* const* d_in, const int* in_sizes, int n_in,
                              void* d_out, int out_size, void* d_ws, size_t ws_size,
                              hipStream_t stream)
{
    const float* t  = (const float*)d_in[0];
    const float* y  = (const float*)d_in[1];
    const float* e  = (const float*)d_in[2];
    const float* W0 = (const float*)d_in[3];
    const float* b0 = (const float*)d_in[4];
    const float* W1 = (const float*)d_in[5];
    const float* b1 = (const float*)d_in[6];
    const float* W2 = (const float*)d_in[7];
    const float* b2 = (const float*)d_in[8];
    float* out = (float*)d_out;

    const int B = in_sizes[1] / 65;
    const int grid = B / RB;

    if (ws_size >= WS_FLOATS * sizeof(float)) {
        prep_kernel<<<(WS_FLOATS + 255) / 256, 256, 0, stream>>>(W0, W1, W2, (float*)d_ws);
        ode_kernel<true><<<grid, NT, 0, stream>>>(t, y, e, W0, b0, W1, b1, W2, b2,
                                                  (const float*)d_ws, out);
    } else {
        ode_kernel<false><<<grid, NT, 0, stream>>>(t, y, e, W0, b0, W1, b1, W2, b2,
                                                   (const float*)d_ws, out);
    }
}

// Round 2
// 656.530 us; speedup vs baseline: 3.8726x; 3.8726x over previous
//
#include <hip/hip_runtime.h>
#include <math.h>

// FFJORD ODE func: 3-layer MLP fwd + VJP + Hutchinson divergence.
// B=262144 rows, D=64, H=256. bf16 MFMA (16x16x32), fp32 accumulate.
//
// ws layout:
//   bf16 packed B-fragments (frag = 512 bf16, MFMA B-layout, frag_id = nt*KT+kt):
//     P0 @ elem 0      : fwd L0  B[s<64][n<256]  = W0[n][1+s]   (KT=2,  32 frags)
//     P1 @ elem 16384  : fwd L1  B[s<256][n<256] = W1[n][1+s]   (KT=8, 128 frags)
//     P2 @ elem 81920  : fwd L2  B[s<256][n<64]  = W2[n][1+s]   (KT=8,  32 frags)
//     P3 @ elem 98304  : bwd g2  B[s<64][n<256]  = W2[s][1+n]   (KT=2,  32 frags)
//     P4 @ elem 114688 : bwd g1  B[s<256][n<256] = W1[s][1+n]   (KT=8, 128 frags)
//     P5 @ elem 180224 : bwd g0  B[s<256][n<64]  = W0[s][1+n]   (KT=8,  32 frags)
//   fp32 cst @ byte 393216: cst0[256], cst1[256], cst2[64] = t*W[:,0]+b

typedef __attribute__((ext_vector_type(8))) short short8;
typedef __attribute__((ext_vector_type(4))) float floatx4;

#define NT 256
#define RB 32
#define LDA 264   // bf16 row stride for 256-wide activations (528 B: 2-way bank alias = free)
#define LDZ 72    // bf16 row stride for 64-wide (z, e)

#define P0_OFF 0
#define P1_OFF 16384
#define P2_OFF 81920
#define P3_OFF 98304
#define P4_OFF 114688
#define P5_OFF 180224
#define PACK_ELEMS 196608
#define CST_BYTE_OFF (PACK_ELEMS * 2)
#define WS_BYTES (CST_BYTE_OFF + 576 * 4)

static __device__ __forceinline__ short f2bf(float f) {
    union { float f; unsigned u; } v; v.f = f;
    unsigned r = v.u + 0x7FFFu + ((v.u >> 16) & 1u);   // RNE
    return (short)(r >> 16);
}
static __device__ __forceinline__ float bf2f(short h) {
    union { unsigned u; float f; } v; v.u = ((unsigned)(unsigned short)h) << 16;
    return v.f;
}
static __device__ __forceinline__ float softplus_f(float x) {
    return fmaxf(x, 0.0f) + log1pf(__expf(-fabsf(x)));
}

__global__ void prep_pack(const float* __restrict__ t,
                          const float* __restrict__ W0, const float* __restrict__ b0,
                          const float* __restrict__ W1, const float* __restrict__ b1,
                          const float* __restrict__ W2, const float* __restrict__ b2,
                          short* __restrict__ wsp)
{
    int i = blockIdx.x * blockDim.x + threadIdx.x;
    if (i < PACK_ELEMS) {
        int jin, KT, ld, mode; const float* src;
        if      (i < P1_OFF) { jin = i - P0_OFF; KT = 2; src = W0; ld = 65;  mode = 0; }
        else if (i < P2_OFF) { jin = i - P1_OFF; KT = 8; src = W1; ld = 257; mode = 0; }
        else if (i < P3_OFF) { jin = i - P2_OFF; KT = 8; src = W2; ld = 257; mode = 0; }
        else if (i < P4_OFF) { jin = i - P3_OFF; KT = 2; src = W2; ld = 257; mode = 1; }
        else if (i < P5_OFF) { jin = i - P4_OFF; KT = 8; src = W1; ld = 257; mode = 1; }
        else                 { jin = i - P5_OFF; KT = 8; src = W0; ld = 65;  mode = 1; }
        int f = jin >> 9, r = jin & 511;
        int lane = r >> 3, jj = r & 7;
        int kt = f % KT, nt = f / KT;
        int k = kt * 32 + (lane >> 4) * 8 + jj;
        int n = nt * 16 + (lane & 15);
        float v = (mode == 0) ? src[n * ld + 1 + k] : src[k * ld + 1 + n];
        wsp[i] = f2bf(v);
    } else if (i < PACK_ELEMS + 576) {
        int ci = i - PACK_ELEMS;
        float tv = t[0];
        float* cst = (float*)((char*)wsp + CST_BYTE_OFF);
        float v;
        if (ci < 256)      v = tv * W0[ci * 65] + b0[ci];
        else if (ci < 512) { int n = ci - 256; v = tv * W1[n * 257] + b1[n]; }
        else               { int n = ci - 512; v = tv * W2[n * 257] + b2[n]; }
        cst[ci] = v;
    }
}

__global__ __launch_bounds__(NT, 2)
void ode_mfma(const float* __restrict__ y, const float* __restrict__ e,
              const short* __restrict__ wsp, float* __restrict__ out)
{
    __shared__ __align__(16) short Az[RB * LDZ];   // z bf16
    __shared__ __align__(16) short Ae[RB * LDZ];   // e bf16
    __shared__ __align__(16) short Ha[RB * LDA];   // h0
    __shared__ __align__(16) short Hb[RB * LDA];   // h1, then p0
    __shared__ __align__(16) short Hc[RB * LDA];   // p1
    __shared__ float divp[2][32];

    const int tid = threadIdx.x;
    const int rowbase = blockIdx.x * RB;
    const int w = tid >> 6, l = tid & 63;
    const int lr = l & 15, lq = l >> 4;
    const int mt = w & 1;      // M-tile (rows mt*16..mt*16+15)
    const int nh = w >> 1;     // N-half
    const float* cst = (const float*)((const char*)wsp + CST_BYTE_OFF);

    // ---- stage z = y[:, :64] and e as bf16 ----
    #pragma unroll
    for (int it = 0; it < 8; ++it) {
        int idx = tid + it * NT;            // 0..2047
        int r = idx >> 6, d = idx & 63;
        Az[r * LDZ + d] = f2bf(y[(rowbase + r) * 65 + d]);
        Ae[r * LDZ + d] = f2bf(e[(rowbase + r) * 64 + d]);
    }
    __syncthreads();

    const floatx4 zero = {0.f, 0.f, 0.f, 0.f};

    // ================= G0: h0 = softplus(z @ P0 + cst0) =================
    {
        floatx4 acc[8];
        #pragma unroll
        for (int n = 0; n < 8; ++n) acc[n] = zero;
        const int nt0 = nh * 8;
        #pragma unroll
        for (int kt = 0; kt < 2; ++kt) {
            short8 a = *(const short8*)&Az[(mt * 16 + lr) * LDZ + kt * 32 + lq * 8];
            #pragma unroll
            for (int n = 0; n < 8; ++n) {
                short8 b = *(const short8*)&wsp[P0_OFF + ((nt0 + n) * 2 + kt) * 512 + l * 8];
                acc[n] = __builtin_amdgcn_mfma_f32_16x16x32_bf16(a, b, acc[n], 0, 0, 0);
            }
        }
        #pragma unroll
        for (int n = 0; n < 8; ++n) {
            int col = (nt0 + n) * 16 + lr;
            float c = cst[col];
            #pragma unroll
            for (int r = 0; r < 4; ++r) {
                int row = mt * 16 + lq * 4 + r;
                Ha[row * LDA + col] = f2bf(softplus_f(acc[n][r] + c));
            }
        }
    }
    __syncthreads();

    // ================= G1: h1 = softplus(h0 @ P1 + cst1) =================
    {
        floatx4 acc[8];
        #pragma unroll
        for (int n = 0; n < 8; ++n) acc[n] = zero;
        const int nt0 = nh * 8;
        #pragma unroll
        for (int kt = 0; kt < 8; ++kt) {
            short8 a = *(const short8*)&Ha[(mt * 16 + lr) * LDA + kt * 32 + lq * 8];
            #pragma unroll
            for (int n = 0; n < 8; ++n) {
                short8 b = *(const short8*)&wsp[P1_OFF + ((nt0 + n) * 8 + kt) * 512 + l * 8];
                acc[n] = __builtin_amdgcn_mfma_f32_16x16x32_bf16(a, b, acc[n], 0, 0, 0);
            }
        }
        #pragma unroll
        for (int n = 0; n < 8; ++n) {
            int col = (nt0 + n) * 16 + lr;
            float c = cst[256 + col];
            #pragma unroll
            for (int r = 0; r < 4; ++r) {
                int row = mt * 16 + lq * 4 + r;
                Hb[row * LDA + col] = f2bf(softplus_f(acc[n][r] + c));
            }
        }
    }
    __syncthreads();

    // ================= G2: dx = h1 @ P2 + cst2 -> out[:, :64] =================
    {
        floatx4 a0 = zero, a1 = zero;
        const int nt0 = nh * 2;
        #pragma unroll
        for (int kt = 0; kt < 8; ++kt) {
            short8 a = *(const short8*)&Hb[(mt * 16 + lr) * LDA + kt * 32 + lq * 8];
            short8 bA = *(const short8*)&wsp[P2_OFF + (nt0 * 8 + kt) * 512 + l * 8];
            short8 bB = *(const short8*)&wsp[P2_OFF + ((nt0 + 1) * 8 + kt) * 512 + l * 8];
            a0 = __builtin_amdgcn_mfma_f32_16x16x32_bf16(a, bA, a0, 0, 0, 0);
            a1 = __builtin_amdgcn_mfma_f32_16x16x32_bf16(a, bB, a1, 0, 0, 0);
        }
        #pragma unroll
        for (int tle = 0; tle < 2; ++tle) {
            int col = (nt0 + tle) * 16 + lr;
            float c = cst[512 + col];
            #pragma unroll
            for (int r = 0; r < 4; ++r) {
                int row = mt * 16 + lq * 4 + r;
                float v = (tle == 0 ? a0[r] : a1[r]) + c;
                out[(rowbase + row) * 65 + col] = v;
            }
        }
    }
    // no barrier needed: G3 writes Hc (fresh), reads Ae/Hb (stable since last barrier)

    // ================= G3: g2 = e @ P3;  p1 = g2 * (1-exp(-h1)) -> Hc =================
    {
        floatx4 acc[8];
        #pragma unroll
        for (int n = 0; n < 8; ++n) acc[n] = zero;
        const int nt0 = nh * 8;
        #pragma unroll
        for (int kt = 0; kt < 2; ++kt) {
            short8 a = *(const short8*)&Ae[(mt * 16 + lr) * LDZ + kt * 32 + lq * 8];
            #pragma unroll
            for (int n = 0; n < 8; ++n) {
                short8 b = *(const short8*)&wsp[P3_OFF + ((nt0 + n) * 2 + kt) * 512 + l * 8];
                acc[n] = __builtin_amdgcn_mfma_f32_16x16x32_bf16(a, b, acc[n], 0, 0, 0);
            }
        }
        #pragma unroll
        for (int n = 0; n < 8; ++n) {
            int col = (nt0 + n) * 16 + lr;
            #pragma unroll
            for (int r = 0; r < 4; ++r) {
                int row = mt * 16 + lq * 4 + r;
                float h1v = bf2f(Hb[row * LDA + col]);
                Hc[row * LDA + col] = f2bf(acc[n][r] * (1.0f - __expf(-h1v)));
            }
        }
    }
    __syncthreads();

    // ================= G4: g1 = p1 @ P4;  p0 = g1 * (1-exp(-h0)) -> Hb =================
    {
        floatx4 acc[8];
        #pragma unroll
        for (int n = 0; n < 8; ++n) acc[n] = zero;
        const int nt0 = nh * 8;
        #pragma unroll
        for (int kt = 0; kt < 8; ++kt) {
            short8 a = *(const short8*)&Hc[(mt * 16 + lr) * LDA + kt * 32 + lq * 8];
            #pragma unroll
            for (int n = 0; n < 8; ++n) {
                short8 b = *(const short8*)&wsp[P4_OFF + ((nt0 + n) * 8 + kt) * 512 + l * 8];
                acc[n] = __builtin_amdgcn_mfma_f32_16x16x32_bf16(a, b, acc[n], 0, 0, 0);
            }
        }
        #pragma unroll
        for (int n = 0; n < 8; ++n) {
            int col = (nt0 + n) * 16 + lr;
            #pragma unroll
            for (int r = 0; r < 4; ++r) {
                int row = mt * 16 + lq * 4 + r;
                float h0v = bf2f(Ha[row * LDA + col]);
                Hb[row * LDA + col] = f2bf(acc[n][r] * (1.0f - __expf(-h0v)));
            }
        }
    }
    __syncthreads();

    // ================= G5: g0 = p0 @ P5;  div = sum(g0 * e);  out[:,64] = -div ====
    {
        floatx4 a0 = zero, a1 = zero;
        const int nt0 = nh * 2;
        #pragma unroll
        for (int kt = 0; kt < 8; ++kt) {
            short8 a = *(const short8*)&Hb[(mt * 16 + lr) * LDA + kt * 32 + lq * 8];
            short8 bA = *(const short8*)&wsp[P5_OFF + (nt0 * 8 + kt) * 512 + l * 8];
            short8 bB = *(const short8*)&wsp[P5_OFF + ((nt0 + 1) * 8 + kt) * 512 + l * 8];
            a0 = __builtin_amdgcn_mfma_f32_16x16x32_bf16(a, bA, a0, 0, 0, 0);
            a1 = __builtin_amdgcn_mfma_f32_16x16x32_bf16(a, bB, a1, 0, 0, 0);
        }
        int c0 = nt0 * 16 + lr, c1 = c0 + 16;
        #pragma unroll
        for (int r = 0; r < 4; ++r) {
            int row = mt * 16 + lq * 4 + r;
            float v = a0[r] * e[(rowbase + row) * 64 + c0]
                    + a1[r] * e[(rowbase + row) * 64 + c1];
            #pragma unroll
            for (int m = 1; m < 16; m <<= 1) v += __shfl_xor(v, m, 64);
            if (lr == 0) divp[nh][row] = v;
        }
    }
    __syncthreads();
    if (tid < 32) out[(rowbase + tid) * 65 + 64] = -(divp[0][tid] + divp[1][tid]);
}

// ---------------- fp32 vector fallback (used only if ws_size too small) ----------------
__global__ __launch_bounds__(NT, 2)
void ode_fallback(const float* __restrict__ tptr,
                  const float* __restrict__ y, const float* __restrict__ e,
                  const float* __restrict__ W0, const float* __restrict__ b0,
                  const float* __restrict__ W1, const float* __restrict__ b1,
                  const float* __restrict__ W2, const float* __restrict__ b2,
                  float* __restrict__ out)
{
    __shared__ float H0[RB * 257];
    __shared__ float H1[RB * 257];
    __shared__ float ZE[RB * 68];

    const int tid = threadIdx.x;
    const int rowbase = blockIdx.x * RB;
    const float tval = tptr[0];
    const int cg = tid & 31, rg = tid >> 5;
    const int cg2 = tid & 15, rg2 = tid >> 4;

    {
        const int d = tid & 63, r0 = tid >> 6;
        for (int r = r0; r < RB; r += NT / 64)
            ZE[r * 68 + d] = y[(rowbase + r) * 65 + d];
    }
    __syncthreads();

    float acc[4][8];
    float acc2[2][4];

    for (int i = 0; i < 4; ++i) for (int j = 0; j < 8; ++j) acc[i][j] = 0.0f;
    for (int s = 0; s < 64; ++s) {
        float b[8];
        for (int j = 0; j < 8; ++j) b[j] = W0[(cg * 8 + j) * 65 + 1 + s];
        float a[4];
        for (int i = 0; i < 4; ++i) a[i] = ZE[(rg * 4 + i) * 68 + s];
        for (int i = 0; i < 4; ++i) for (int j = 0; j < 8; ++j)
            acc[i][j] = fmaf(a[i], b[j], acc[i][j]);
    }
    for (int i = 0; i < 4; ++i) for (int j = 0; j < 8; ++j) {
        int n = cg * 8 + j;
        H0[(rg * 4 + i) * 257 + n] = softplus_f(acc[i][j] + tval * W0[n * 65] + b0[n]);
    }
    __syncthreads();

    for (int idx = tid; idx < RB * 16; idx += NT) {
        int r = idx >> 4, c = idx & 15;
        *(float4*)(&ZE[r * 68 + c * 4]) = *(const float4*)(e + (rowbase + r) * 64 + c * 4);
    }

    for (int i = 0; i < 4; ++i) for (int j = 0; j < 8; ++j) acc[i][j] = 0.0f;
    for (int s = 0; s < 256; ++s) {
        float b[8];
        for (int j = 0; j < 8; ++j) b[j] = W1[(cg * 8 + j) * 257 + 1 + s];
        float a[4];
        for (int i = 0; i < 4; ++i) a[i] = H0[(rg * 4 + i) * 257 + s];
        for (int i = 0; i < 4; ++i) for (int j = 0; j < 8; ++j)
            acc[i][j] = fmaf(a[i], b[j], acc[i][j]);
    }
    for (int i = 0; i < 4; ++i) for (int j = 0; j < 8; ++j) {
        int n = cg * 8 + j;
        H1[(rg * 4 + i) * 257 + n] = softplus_f(acc[i][j] + tval * W1[n * 257] + b1[n]);
    }
    __syncthreads();

    for (int i = 0; i < 2; ++i) for (int j = 0; j < 4; ++j) acc2[i][j] = 0.0f;
    for (int s = 0; s < 256; ++s) {
        float b[4];
        for (int j = 0; j < 4; ++j) b[j] = W2[(cg2 * 4 + j) * 257 + 1 + s];
        float a[2];
        for (int i = 0; i < 2; ++i) a[i] = H1[(rg2 * 2 + i) * 257 + s];
        for (int i = 0; i < 2; ++i) for (int j = 0; j < 4; ++j)
            acc2[i][j] = fmaf(a[i], b[j], acc2[i][j]);
    }
    for (int i = 0; i < 2; ++i) for (int j = 0; j < 4; ++j) {
        int n = cg2 * 4 + j;
        out[(rowbase + rg2 * 2 + i) * 65 + n] = acc2[i][j] + tval * W2[n * 257] + b2[n];
    }
    __syncthreads();

    for (int i = 0; i < 4; ++i) for (int j = 0; j < 8; ++j) acc[i][j] = 0.0f;
    for (int s = 0; s < 64; ++s) {
        float b[8];
        for (int j = 0; j < 8; ++j) b[j] = W2[s * 257 + 1 + cg * 8 + j];
        float a[4];
        for (int i = 0; i < 4; ++i) a[i] = ZE[(rg * 4 + i) * 68 + s];
        for (int i = 0; i < 4; ++i) for (int j = 0; j < 8; ++j)
            acc[i][j] = fmaf(a[i], b[j], acc[i][j]);
    }
    for (int i = 0; i < 4; ++i) for (int j = 0; j < 8; ++j) {
        int r = rg * 4 + i, n = cg * 8 + j;
        float h = H1[r * 257 + n];
        H1[r * 257 + n] = acc[i][j] * (1.0f - __expf(-h));
    }
    __syncthreads();

    for (int i = 0; i < 4; ++i) for (int j = 0; j < 8; ++j) acc[i][j] = 0.0f;
    for (int s = 0; s < 256; ++s) {
        float b[8];
        for (int j = 0; j < 8; ++j) b[j] = W1[s * 257 + 1 + cg * 8 + j];
        float a[4];
        for (int i = 0; i < 4; ++i) a[i] = H1[(rg * 4 + i) * 257 + s];
        for (int i = 0; i < 4; ++i) for (int j = 0; j < 8; ++j)
            acc[i][j] = fmaf(a[i], b[j], acc[i][j]);
    }
    for (int i = 0; i < 4; ++i) for (int j = 0; j < 8; ++j) {
        int r = rg * 4 + i, n = cg * 8 + j;
        float h = H0[r * 257 + n];
        H0[r * 257 + n] = acc[i][j] * (1.0f - __expf(-h));
    }
    __syncthreads();

    for (int i = 0; i < 2; ++i) for (int j = 0; j < 4; ++j) acc2[i][j] = 0.0f;
    for (int s = 0; s < 256; ++s) {
        float b[4];
        for (int j = 0; j < 4; ++j) b[j] = W0[s * 65 + 1 + cg2 * 4 + j];
        float a[2];
        for (int i = 0; i < 2; ++i) a[i] = H0[(rg2 * 2 + i) * 257 + s];
        for (int i = 0; i < 2; ++i) for (int j = 0; j < 4; ++j)
            acc2[i][j] = fmaf(a[i], b[j], acc2[i][j]);
    }
    float pA = 0.0f, pB = 0.0f;
    for (int j = 0; j < 4; ++j) {
        int n = cg2 * 4 + j;
        pA = fmaf(acc2[0][j], ZE[(rg2 * 2 + 0) * 68 + n], pA);
        pB = fmaf(acc2[1][j], ZE[(rg2 * 2 + 1) * 68 + n], pB);
    }
    for (int off = 8; off > 0; off >>= 1) {
        pA += __shfl_down(pA, off, 16);
        pB += __shfl_down(pB, off, 16);
    }
    if (cg2 == 0) {
        out[(rowbase + rg2 * 2 + 0) * 65 + 64] = -pA;
        out[(rowbase + rg2 * 2 + 1) * 65 + 64] = -pB;
    }
}

extern "C" void kernel_launch(void* const* d_in, const int* in_sizes, int n_in,
                              void* d_out, int out_size, void* d_ws, size_t ws_size,
                              hipStream_t stream)
{
    const float* t  = (const float*)d_in[0];
    const float* y  = (const float*)d_in[1];
    const float* e  = (const float*)d_in[2];
    const float* W0 = (const float*)d_in[3];
    const float* b0 = (const float*)d_in[4];
    const float* W1 = (const float*)d_in[5];
    const float* b1 = (const float*)d_in[6];
    const float* W2 = (const float*)d_in[7];
    const float* b2 = (const float*)d_in[8];
    float* out = (float*)d_out;

    const int B = in_sizes[1] / 65;

    if (ws_size >= (size_t)WS_BYTES) {
        prep_pack<<<(PACK_ELEMS + 576 + 255) / 256, 256, 0, stream>>>(
            t, W0, b0, W1, b1, W2, b2, (short*)d_ws);
        ode_mfma<<<B / RB, NT, 0, stream>>>(y, e, (const short*)d_ws, out);
    } else {
        ode_fallback<<<B / RB, NT, 0, stream>>>(t, y, e, W0, b0, W1, b1, W2, b2, out);
    }
}

// Round 3
// 407.889 us; speedup vs baseline: 6.2333x; 1.6096x over previous
//
#include <hip/hip_runtime.h>
#include <math.h>

// FFJORD ODE func: 3-layer MLP fwd + VJP + Hutchinson divergence.
// B=262144 rows, D=64, H=256. bf16 MFMA (16x16x32), fp32 accumulate.
// R3: 8 waves/block (N split 4 ways), fast softplus/sigmoid (native exp/log).
//
// ws layout:
//   bf16 packed B-fragments (frag = 512 bf16, MFMA B-layout, frag_id = nt*KT+kt):
//     P0 @ elem 0      : fwd L0  B[s<64][n<256]  = W0[n][1+s]   (KT=2,  32 frags)
//     P1 @ elem 16384  : fwd L1  B[s<256][n<256] = W1[n][1+s]   (KT=8, 128 frags)
//     P2 @ elem 81920  : fwd L2  B[s<256][n<64]  = W2[n][1+s]   (KT=8,  32 frags)
//     P3 @ elem 98304  : bwd g2  B[s<64][n<256]  = W2[s][1+n]   (KT=2,  32 frags)
//     P4 @ elem 114688 : bwd g1  B[s<256][n<256] = W1[s][1+n]   (KT=8, 128 frags)
//     P5 @ elem 180224 : bwd g0  B[s<256][n<64]  = W0[s][1+n]   (KT=8,  32 frags)
//   fp32 cst @ byte 393216: cst0[256], cst1[256], cst2[64] = t*W[:,0]+b

typedef __attribute__((ext_vector_type(8))) short short8;
typedef __attribute__((ext_vector_type(4))) float floatx4;

#define NT 512    // 8 waves
#define RB 32
#define LDA 264   // bf16 row stride, 528 B (16B-aligned rows; 2-bank row shift = free aliasing)
#define LDZ 72

#define P0_OFF 0
#define P1_OFF 16384
#define P2_OFF 81920
#define P3_OFF 98304
#define P4_OFF 114688
#define P5_OFF 180224
#define PACK_ELEMS 196608
#define CST_BYTE_OFF (PACK_ELEMS * 2)
#define WS_BYTES (CST_BYTE_OFF + 576 * 4)

static __device__ __forceinline__ short f2bf(float f) {
    union { float f; unsigned u; } v; v.f = f;
    unsigned r = v.u + 0x7FFFu + ((v.u >> 16) & 1u);   // RNE
    return (short)(r >> 16);
}
static __device__ __forceinline__ float bf2f(short h) {
    union { unsigned u; float f; } v; v.u = ((unsigned)(unsigned short)h) << 16;
    return v.f;
}
// Fast softplus: error vs log1p formulation is ~2^-24 absolute -> invisible after
// bf16 storage (2^-9 relative). Native v_exp_f32 / v_log_f32 only, ~7 VALU ops.
static __device__ __forceinline__ float softplus_fast(float x) {
    float u = __expf(-fabsf(x));
    return fmaxf(x, 0.0f) + __logf(1.0f + u);
}

__global__ void prep_pack(const float* __restrict__ t,
                          const float* __restrict__ W0, const float* __restrict__ b0,
                          const float* __restrict__ W1, const float* __restrict__ b1,
                          const float* __restrict__ W2, const float* __restrict__ b2,
                          short* __restrict__ wsp)
{
    int i = blockIdx.x * blockDim.x + threadIdx.x;
    if (i < PACK_ELEMS) {
        int jin, KT, ld, mode; const float* src;
        if      (i < P1_OFF) { jin = i - P0_OFF; KT = 2; src = W0; ld = 65;  mode = 0; }
        else if (i < P2_OFF) { jin = i - P1_OFF; KT = 8; src = W1; ld = 257; mode = 0; }
        else if (i < P3_OFF) { jin = i - P2_OFF; KT = 8; src = W2; ld = 257; mode = 0; }
        else if (i < P4_OFF) { jin = i - P3_OFF; KT = 2; src = W2; ld = 257; mode = 1; }
        else if (i < P5_OFF) { jin = i - P4_OFF; KT = 8; src = W1; ld = 257; mode = 1; }
        else                 { jin = i - P5_OFF; KT = 8; src = W0; ld = 65;  mode = 1; }
        int f = jin >> 9, r = jin & 511;
        int lane = r >> 3, jj = r & 7;
        int kt = f % KT, nt = f / KT;
        int k = kt * 32 + (lane >> 4) * 8 + jj;
        int n = nt * 16 + (lane & 15);
        float v = (mode == 0) ? src[n * ld + 1 + k] : src[k * ld + 1 + n];
        wsp[i] = f2bf(v);
    } else if (i < PACK_ELEMS + 576) {
        int ci = i - PACK_ELEMS;
        float tv = t[0];
        float* cst = (float*)((char*)wsp + CST_BYTE_OFF);
        float v;
        if (ci < 256)      v = tv * W0[ci * 65] + b0[ci];
        else if (ci < 512) { int n = ci - 256; v = tv * W1[n * 257] + b1[n]; }
        else               { int n = ci - 512; v = tv * W2[n * 257] + b2[n]; }
        cst[ci] = v;
    }
}

__global__ __launch_bounds__(NT, 4)   // 4 waves/EU -> 2 blocks/CU (8-wave blocks)
void ode_mfma(const float* __restrict__ y, const float* __restrict__ e,
              const short* __restrict__ wsp, float* __restrict__ out)
{
    __shared__ __align__(16) short Az[RB * LDZ];   // z bf16
    __shared__ __align__(16) short Ae[RB * LDZ];   // e bf16
    __shared__ __align__(16) short Ha[RB * LDA];   // h0
    __shared__ __align__(16) short Hb[RB * LDA];   // h1, then p0
    __shared__ __align__(16) short Hc[RB * LDA];   // p1
    __shared__ float divp[4][RB];

    const int tid = threadIdx.x;
    const int rowbase = blockIdx.x * RB;
    const int w = tid >> 6, l = tid & 63;
    const int lr = l & 15, lq = l >> 4;
    const int mt = w & 1;      // M-tile (rows mt*16 .. mt*16+15)
    const int nq = w >> 1;     // N-quarter (0..3)
    const float* cst = (const float*)((const char*)wsp + CST_BYTE_OFF);

    // ---- stage z = y[:, :64] and e as bf16 ----
    #pragma unroll
    for (int it = 0; it < 4; ++it) {
        int idx = tid + it * NT;            // 0..2047
        int r = idx >> 6, d = idx & 63;
        Az[r * LDZ + d] = f2bf(y[(rowbase + r) * 65 + d]);
        Ae[r * LDZ + d] = f2bf(e[(rowbase + r) * 64 + d]);
    }
    __syncthreads();

    const floatx4 zero = {0.f, 0.f, 0.f, 0.f};
    const int arow = (mt * 16 + lr);

    // ================= G0: h0 = softplus(z @ P0 + cst0) =================
    {
        floatx4 acc[4];
        #pragma unroll
        for (int n = 0; n < 4; ++n) acc[n] = zero;
        const int nt0 = nq * 4;
        #pragma unroll
        for (int kt = 0; kt < 2; ++kt) {
            short8 a = *(const short8*)&Az[arow * LDZ + kt * 32 + lq * 8];
            #pragma unroll
            for (int n = 0; n < 4; ++n) {
                short8 b = *(const short8*)&wsp[P0_OFF + ((nt0 + n) * 2 + kt) * 512 + l * 8];
                acc[n] = __builtin_amdgcn_mfma_f32_16x16x32_bf16(a, b, acc[n], 0, 0, 0);
            }
        }
        #pragma unroll
        for (int n = 0; n < 4; ++n) {
            int col = (nt0 + n) * 16 + lr;
            float c = cst[col];
            #pragma unroll
            for (int r = 0; r < 4; ++r) {
                int row = mt * 16 + lq * 4 + r;
                Ha[row * LDA + col] = f2bf(softplus_fast(acc[n][r] + c));
            }
        }
    }
    __syncthreads();

    // ================= G1: h1 = softplus(h0 @ P1 + cst1) =================
    {
        floatx4 acc[4];
        #pragma unroll
        for (int n = 0; n < 4; ++n) acc[n] = zero;
        const int nt0 = nq * 4;
        #pragma unroll
        for (int kt = 0; kt < 8; ++kt) {
            short8 a = *(const short8*)&Ha[arow * LDA + kt * 32 + lq * 8];
            #pragma unroll
            for (int n = 0; n < 4; ++n) {
                short8 b = *(const short8*)&wsp[P1_OFF + ((nt0 + n) * 8 + kt) * 512 + l * 8];
                acc[n] = __builtin_amdgcn_mfma_f32_16x16x32_bf16(a, b, acc[n], 0, 0, 0);
            }
        }
        #pragma unroll
        for (int n = 0; n < 4; ++n) {
            int col = (nt0 + n) * 16 + lr;
            float c = cst[256 + col];
            #pragma unroll
            for (int r = 0; r < 4; ++r) {
                int row = mt * 16 + lq * 4 + r;
                Hb[row * LDA + col] = f2bf(softplus_fast(acc[n][r] + c));
            }
        }
    }
    __syncthreads();

    // ================= G2: dx = h1 @ P2 + cst2 -> out[:, :64] =================
    {
        floatx4 a0 = zero;
        #pragma unroll
        for (int kt = 0; kt < 8; ++kt) {
            short8 a = *(const short8*)&Hb[arow * LDA + kt * 32 + lq * 8];
            short8 b = *(const short8*)&wsp[P2_OFF + (nq * 8 + kt) * 512 + l * 8];
            a0 = __builtin_amdgcn_mfma_f32_16x16x32_bf16(a, b, a0, 0, 0, 0);
        }
        int col = nq * 16 + lr;
        float c = cst[512 + col];
        #pragma unroll
        for (int r = 0; r < 4; ++r) {
            int row = mt * 16 + lq * 4 + r;
            out[(rowbase + row) * 65 + col] = a0[r] + c;
        }
    }
    // no barrier: G3 writes Hc (fresh), reads Ae/Hb (stable since their barriers)

    // ================= G3: g2 = e @ P3;  p1 = g2 * (1-exp(-h1)) -> Hc =================
    {
        floatx4 acc[4];
        #pragma unroll
        for (int n = 0; n < 4; ++n) acc[n] = zero;
        const int nt0 = nq * 4;
        #pragma unroll
        for (int kt = 0; kt < 2; ++kt) {
            short8 a = *(const short8*)&Ae[arow * LDZ + kt * 32 + lq * 8];
            #pragma unroll
            for (int n = 0; n < 4; ++n) {
                short8 b = *(const short8*)&wsp[P3_OFF + ((nt0 + n) * 2 + kt) * 512 + l * 8];
                acc[n] = __builtin_amdgcn_mfma_f32_16x16x32_bf16(a, b, acc[n], 0, 0, 0);
            }
        }
        #pragma unroll
        for (int n = 0; n < 4; ++n) {
            int col = (nt0 + n) * 16 + lr;
            #pragma unroll
            for (int r = 0; r < 4; ++r) {
                int row = mt * 16 + lq * 4 + r;
                float g  = acc[n][r];
                float ex = __expf(-bf2f(Hb[row * LDA + col]));
                Hc[row * LDA + col] = f2bf(fmaf(-g, ex, g));   // g * (1 - exp(-h1))
            }
        }
    }
    __syncthreads();

    // ================= G4: g1 = p1 @ P4;  p0 = g1 * (1-exp(-h0)) -> Hb =================
    {
        floatx4 acc[4];
        #pragma unroll
        for (int n = 0; n < 4; ++n) acc[n] = zero;
        const int nt0 = nq * 4;
        #pragma unroll
        for (int kt = 0; kt < 8; ++kt) {
            short8 a = *(const short8*)&Hc[arow * LDA + kt * 32 + lq * 8];
            #pragma unroll
            for (int n = 0; n < 4; ++n) {
                short8 b = *(const short8*)&wsp[P4_OFF + ((nt0 + n) * 8 + kt) * 512 + l * 8];
                acc[n] = __builtin_amdgcn_mfma_f32_16x16x32_bf16(a, b, acc[n], 0, 0, 0);
            }
        }
        #pragma unroll
        for (int n = 0; n < 4; ++n) {
            int col = (nt0 + n) * 16 + lr;
            #pragma unroll
            for (int r = 0; r < 4; ++r) {
                int row = mt * 16 + lq * 4 + r;
                float g  = acc[n][r];
                float ex = __expf(-bf2f(Ha[row * LDA + col]));
                Hb[row * LDA + col] = f2bf(fmaf(-g, ex, g));   // g * (1 - exp(-h0))
            }
        }
    }
    __syncthreads();

    // ================= G5: g0 = p0 @ P5;  div = sum(g0 * e);  out[:,64] = -div ====
    {
        floatx4 a0 = zero;
        #pragma unroll
        for (int kt = 0; kt < 8; ++kt) {
            short8 a = *(const short8*)&Hb[arow * LDA + kt * 32 + lq * 8];
            short8 b = *(const short8*)&wsp[P5_OFF + (nq * 8 + kt) * 512 + l * 8];
            a0 = __builtin_amdgcn_mfma_f32_16x16x32_bf16(a, b, a0, 0, 0, 0);
        }
        int col = nq * 16 + lr;
        #pragma unroll
        for (int r = 0; r < 4; ++r) {
            int row = mt * 16 + lq * 4 + r;
            float v = a0[r] * e[(rowbase + row) * 64 + col];
            #pragma unroll
            for (int m = 1; m < 16; m <<= 1) v += __shfl_xor(v, m, 64);
            if (lr == 0) divp[nq][row] = v;
        }
    }
    __syncthreads();
    if (tid < RB)
        out[(rowbase + tid) * 65 + 64] =
            -(divp[0][tid] + divp[1][tid] + divp[2][tid] + divp[3][tid]);
}

// ---------------- fp32 vector fallback (used only if ws_size too small) ----------------
#define FNT 256
__global__ __launch_bounds__(FNT, 2)
void ode_fallback(const float* __restrict__ tptr,
                  const float* __restrict__ y, const float* __restrict__ e,
                  const float* __restrict__ W0, const float* __restrict__ b0,
                  const float* __restrict__ W1, const float* __restrict__ b1,
                  const float* __restrict__ W2, const float* __restrict__ b2,
                  float* __restrict__ out)
{
    __shared__ float H0[RB * 257];
    __shared__ float H1[RB * 257];
    __shared__ float ZE[RB * 68];

    const int tid = threadIdx.x;
    const int rowbase = blockIdx.x * RB;
    const float tval = tptr[0];
    const int cg = tid & 31, rg = tid >> 5;
    const int cg2 = tid & 15, rg2 = tid >> 4;

    {
        const int d = tid & 63, r0 = tid >> 6;
        for (int r = r0; r < RB; r += FNT / 64)
            ZE[r * 68 + d] = y[(rowbase + r) * 65 + d];
    }
    __syncthreads();

    float acc[4][8];
    float acc2[2][4];

    for (int i = 0; i < 4; ++i) for (int j = 0; j < 8; ++j) acc[i][j] = 0.0f;
    for (int s = 0; s < 64; ++s) {
        float b[8];
        for (int j = 0; j < 8; ++j) b[j] = W0[(cg * 8 + j) * 65 + 1 + s];
        float a[4];
        for (int i = 0; i < 4; ++i) a[i] = ZE[(rg * 4 + i) * 68 + s];
        for (int i = 0; i < 4; ++i) for (int j = 0; j < 8; ++j)
            acc[i][j] = fmaf(a[i], b[j], acc[i][j]);
    }
    for (int i = 0; i < 4; ++i) for (int j = 0; j < 8; ++j) {
        int n = cg * 8 + j;
        H0[(rg * 4 + i) * 257 + n] = softplus_fast(acc[i][j] + tval * W0[n * 65] + b0[n]);
    }
    __syncthreads();

    for (int idx = tid; idx < RB * 16; idx += FNT) {
        int r = idx >> 4, c = idx & 15;
        *(float4*)(&ZE[r * 68 + c * 4]) = *(const float4*)(e + (rowbase + r) * 64 + c * 4);
    }

    for (int i = 0; i < 4; ++i) for (int j = 0; j < 8; ++j) acc[i][j] = 0.0f;
    for (int s = 0; s < 256; ++s) {
        float b[8];
        for (int j = 0; j < 8; ++j) b[j] = W1[(cg * 8 + j) * 257 + 1 + s];
        float a[4];
        for (int i = 0; i < 4; ++i) a[i] = H0[(rg * 4 + i) * 257 + s];
        for (int i = 0; i < 4; ++i) for (int j = 0; j < 8; ++j)
            acc[i][j] = fmaf(a[i], b[j], acc[i][j]);
    }
    for (int i = 0; i < 4; ++i) for (int j = 0; j < 8; ++j) {
        int n = cg * 8 + j;
        H1[(rg * 4 + i) * 257 + n] = softplus_fast(acc[i][j] + tval * W1[n * 257] + b1[n]);
    }
    __syncthreads();

    for (int i = 0; i < 2; ++i) for (int j = 0; j < 4; ++j) acc2[i][j] = 0.0f;
    for (int s = 0; s < 256; ++s) {
        float b[4];
        for (int j = 0; j < 4; ++j) b[j] = W2[(cg2 * 4 + j) * 257 + 1 + s];
        float a[2];
        for (int i = 0; i < 2; ++i) a[i] = H1[(rg2 * 2 + i) * 257 + s];
        for (int i = 0; i < 2; ++i) for (int j = 0; j < 4; ++j)
            acc2[i][j] = fmaf(a[i], b[j], acc2[i][j]);
    }
    for (int i = 0; i < 2; ++i) for (int j = 0; j < 4; ++j) {
        int n = cg2 * 4 + j;
        out[(rowbase + rg2 * 2 + i) * 65 + n] = acc2[i][j] + tval * W2[n * 257] + b2[n];
    }
    __syncthreads();

    for (int i = 0; i < 4; ++i) for (int j = 0; j < 8; ++j) acc[i][j] = 0.0f;
    for (int s = 0; s < 64; ++s) {
        float b[8];
        for (int j = 0; j < 8; ++j) b[j] = W2[s * 257 + 1 + cg * 8 + j];
        float a[4];
        for (int i = 0; i < 4; ++i) a[i] = ZE[(rg * 4 + i) * 68 + s];
        for (int i = 0; i < 4; ++i) for (int j = 0; j < 8; ++j)
            acc[i][j] = fmaf(a[i], b[j], acc[i][j]);
    }
    for (int i = 0; i < 4; ++i) for (int j = 0; j < 8; ++j) {
        int r = rg * 4 + i, n = cg * 8 + j;
        float h = H1[r * 257 + n];
        H1[r * 257 + n] = acc[i][j] * (1.0f - __expf(-h));
    }
    __syncthreads();

    for (int i = 0; i < 4; ++i) for (int j = 0; j < 8; ++j) acc[i][j] = 0.0f;
    for (int s = 0; s < 256; ++s) {
        float b[8];
        for (int j = 0; j < 8; ++j) b[j] = W1[s * 257 + 1 + cg * 8 + j];
        float a[4];
        for (int i = 0; i < 4; ++i) a[i] = H1[(rg * 4 + i) * 257 + s];
        for (int i = 0; i < 4; ++i) for (int j = 0; j < 8; ++j)
            acc[i][j] = fmaf(a[i], b[j], acc[i][j]);
    }
    for (int i = 0; i < 4; ++i) for (int j = 0; j < 8; ++j) {
        int r = rg * 4 + i, n = cg * 8 + j;
        float h = H0[r * 257 + n];
        H0[r * 257 + n] = acc[i][j] * (1.0f - __expf(-h));
    }
    __syncthreads();

    for (int i = 0; i < 2; ++i) for (int j = 0; j < 4; ++j) acc2[i][j] = 0.0f;
    for (int s = 0; s < 256; ++s) {
        float b[4];
        for (int j = 0; j < 4; ++j) b[j] = W0[s * 65 + 1 + cg2 * 4 + j];
        float a[2];
        for (int i = 0; i < 2; ++i) a[i] = H0[(rg2 * 2 + i) * 257 + s];
        for (int i = 0; i < 2; ++i) for (int j = 0; j < 4; ++j)
            acc2[i][j] = fmaf(a[i], b[j], acc2[i][j]);
    }
    float pA = 0.0f, pB = 0.0f;
    for (int j = 0; j < 4; ++j) {
        int n = cg2 * 4 + j;
        pA = fmaf(acc2[0][j], ZE[(rg2 * 2 + 0) * 68 + n], pA);
        pB = fmaf(acc2[1][j], ZE[(rg2 * 2 + 1) * 68 + n], pB);
    }
    for (int off = 8; off > 0; off >>= 1) {
        pA += __shfl_down(pA, off, 16);
        pB += __shfl_down(pB, off, 16);
    }
    if (cg2 == 0) {
        out[(rowbase + rg2 * 2 + 0) * 65 + 64] = -pA;
        out[(rowbase + rg2 * 2 + 1) * 65 + 64] = -pB;
    }
}

extern "C" void kernel_launch(void* const* d_in, const int* in_sizes, int n_in,
                              void* d_out, int out_size, void* d_ws, size_t ws_size,
                              hipStream_t stream)
{
    const float* t  = (const float*)d_in[0];
    const float* y  = (const float*)d_in[1];
    const float* e  = (const float*)d_in[2];
    const float* W0 = (const float*)d_in[3];
    const float* b0 = (const float*)d_in[4];
    const float* W1 = (const float*)d_in[5];
    const float* b1 = (const float*)d_in[6];
    const float* W2 = (const float*)d_in[7];
    const float* b2 = (const float*)d_in[8];
    float* out = (float*)d_out;

    const int B = in_sizes[1] / 65;

    if (ws_size >= (size_t)WS_BYTES) {
        prep_pack<<<(PACK_ELEMS + 576 + 255) / 256, 256, 0, stream>>>(
            t, W0, b0, W1, b1, W2, b2, (short*)d_ws);
        ode_mfma<<<B / RB, NT, 0, stream>>>(y, e, (const short*)d_ws, out);
    } else {
        ode_fallback<<<B / RB, FNT, 0, stream>>>(t, y, e, W0, b0, W1, b1, W2, b2, out);
    }
}

// Round 4
// 336.540 us; speedup vs baseline: 7.5548x; 1.2120x over previous
//
#include <hip/hip_runtime.h>
#include <math.h>

// FFJORD ODE func: 3-layer MLP fwd + VJP + Hutchinson divergence.
// B=262144 rows, D=64, H=256. bf16 MFMA (16x16x32), fp32 accumulate.
// R4: wave owns BOTH 16-row M-tiles (B-frag reuse x2 -> L2 traffic halves),
//     p1/p0 overwrite h1/h0 in place (LDS 60.4 -> 43.5 KB -> 3 blocks/CU).
//
// ws layout:
//   bf16 packed B-fragments (frag = 512 bf16, MFMA B-layout, frag_id = nt*KT+kt):
//     P0 @ elem 0      : fwd L0  B[s<64][n<256]  = W0[n][1+s]   (KT=2,  32 frags)
//     P1 @ elem 16384  : fwd L1  B[s<256][n<256] = W1[n][1+s]   (KT=8, 128 frags)
//     P2 @ elem 81920  : fwd L2  B[s<256][n<64]  = W2[n][1+s]   (KT=8,  32 frags)
//     P3 @ elem 98304  : bwd g2  B[s<64][n<256]  = W2[s][1+n]   (KT=2,  32 frags)
//     P4 @ elem 114688 : bwd g1  B[s<256][n<256] = W1[s][1+n]   (KT=8, 128 frags)
//     P5 @ elem 180224 : bwd g0  B[s<256][n<64]  = W0[s][1+n]   (KT=8,  32 frags)
//   fp32 cst @ byte 393216: cst0[256], cst1[256], cst2[64] = t*W[:,0]+b

typedef __attribute__((ext_vector_type(8))) short short8;
typedef __attribute__((ext_vector_type(4))) float floatx4;

#define NT 512    // 8 waves
#define RB 32
#define LDA 264   // bf16 row stride (528 B, 16B-aligned rows)
#define LDZ 72

#define P0_OFF 0
#define P1_OFF 16384
#define P2_OFF 81920
#define P3_OFF 98304
#define P4_OFF 114688
#define P5_OFF 180224
#define PACK_ELEMS 196608
#define CST_BYTE_OFF (PACK_ELEMS * 2)
#define WS_BYTES (CST_BYTE_OFF + 576 * 4)

static __device__ __forceinline__ short f2bf(float f) {
    union { float f; unsigned u; } v; v.f = f;
    unsigned r = v.u + 0x7FFFu + ((v.u >> 16) & 1u);   // RNE
    return (short)(r >> 16);
}
static __device__ __forceinline__ float bf2f(short h) {
    union { unsigned u; float f; } v; v.u = ((unsigned)(unsigned short)h) << 16;
    return v.f;
}
// Fast softplus: native v_exp_f32/v_log_f32; error ~2^-24 abs, invisible at bf16.
static __device__ __forceinline__ float softplus_fast(float x) {
    float u = __expf(-fabsf(x));
    return fmaxf(x, 0.0f) + __logf(1.0f + u);
}

__global__ void prep_pack(const float* __restrict__ t,
                          const float* __restrict__ W0, const float* __restrict__ b0,
                          const float* __restrict__ W1, const float* __restrict__ b1,
                          const float* __restrict__ W2, const float* __restrict__ b2,
                          short* __restrict__ wsp)
{
    int i = blockIdx.x * blockDim.x + threadIdx.x;
    if (i < PACK_ELEMS) {
        int jin, KT, ld, mode; const float* src;
        if      (i < P1_OFF) { jin = i - P0_OFF; KT = 2; src = W0; ld = 65;  mode = 0; }
        else if (i < P2_OFF) { jin = i - P1_OFF; KT = 8; src = W1; ld = 257; mode = 0; }
        else if (i < P3_OFF) { jin = i - P2_OFF; KT = 8; src = W2; ld = 257; mode = 0; }
        else if (i < P4_OFF) { jin = i - P3_OFF; KT = 2; src = W2; ld = 257; mode = 1; }
        else if (i < P5_OFF) { jin = i - P4_OFF; KT = 8; src = W1; ld = 257; mode = 1; }
        else                 { jin = i - P5_OFF; KT = 8; src = W0; ld = 65;  mode = 1; }
        int f = jin >> 9, r = jin & 511;
        int lane = r >> 3, jj = r & 7;
        int kt = f % KT, nt = f / KT;
        int k = kt * 32 + (lane >> 4) * 8 + jj;
        int n = nt * 16 + (lane & 15);
        float v = (mode == 0) ? src[n * ld + 1 + k] : src[k * ld + 1 + n];
        wsp[i] = f2bf(v);
    } else if (i < PACK_ELEMS + 576) {
        int ci = i - PACK_ELEMS;
        float tv = t[0];
        float* cst = (float*)((char*)wsp + CST_BYTE_OFF);
        float v;
        if (ci < 256)      v = tv * W0[ci * 65] + b0[ci];
        else if (ci < 512) { int n = ci - 256; v = tv * W1[n * 257] + b1[n]; }
        else               { int n = ci - 512; v = tv * W2[n * 257] + b2[n]; }
        cst[ci] = v;
    }
}

__global__ __launch_bounds__(NT, 6)   // 6 waves/EU -> 3 blocks/CU (8-wave blocks)
void ode_mfma(const float* __restrict__ y, const float* __restrict__ e,
              const short* __restrict__ wsp, float* __restrict__ out)
{
    __shared__ __align__(16) short Az[RB * LDZ];   // z bf16
    __shared__ __align__(16) short Ae[RB * LDZ];   // e bf16
    __shared__ __align__(16) short Ha[RB * LDA];   // h0, then p0 (in place)
    __shared__ __align__(16) short Hb[RB * LDA];   // h1, then p1 (in place)
    __shared__ float divp[4][RB];

    const int tid = threadIdx.x;
    const int rowbase = blockIdx.x * RB;
    const int w = tid >> 6, l = tid & 63;
    const int lr = l & 15, lq = l >> 4;
    // 256-col GEMMs (G0,G1,G3,G4): wave w owns N-eighth w (2 n-tiles), BOTH m-tiles.
    const int ne = w;
    // 64-col GEMMs (G2,G5): wave = (mt, nq) as before.
    const int mt = w & 1, nq = w >> 1;
    const float* cst = (const float*)((const char*)wsp + CST_BYTE_OFF);

    // ---- stage z = y[:, :64] and e as bf16 ----
    #pragma unroll
    for (int it = 0; it < 4; ++it) {
        int idx = tid + it * NT;            // 0..2047
        int r = idx >> 6, d = idx & 63;
        Az[r * LDZ + d] = f2bf(y[(rowbase + r) * 65 + d]);
        Ae[r * LDZ + d] = f2bf(e[(rowbase + r) * 64 + d]);
    }
    __syncthreads();

    const floatx4 zero = {0.f, 0.f, 0.f, 0.f};

    // ================= G0: h0 = softplus(z @ P0 + cst0) =================
    {
        floatx4 acc[2][2];   // [m][n]
        acc[0][0] = zero; acc[0][1] = zero; acc[1][0] = zero; acc[1][1] = zero;
        const int nt0 = ne * 2;
        #pragma unroll
        for (int kt = 0; kt < 2; ++kt) {
            short8 a0 = *(const short8*)&Az[lr * LDZ + kt * 32 + lq * 8];
            short8 a1 = *(const short8*)&Az[(16 + lr) * LDZ + kt * 32 + lq * 8];
            short8 b0 = *(const short8*)&wsp[P0_OFF + ((nt0 + 0) * 2 + kt) * 512 + l * 8];
            short8 b1 = *(const short8*)&wsp[P0_OFF + ((nt0 + 1) * 2 + kt) * 512 + l * 8];
            acc[0][0] = __builtin_amdgcn_mfma_f32_16x16x32_bf16(a0, b0, acc[0][0], 0, 0, 0);
            acc[0][1] = __builtin_amdgcn_mfma_f32_16x16x32_bf16(a0, b1, acc[0][1], 0, 0, 0);
            acc[1][0] = __builtin_amdgcn_mfma_f32_16x16x32_bf16(a1, b0, acc[1][0], 0, 0, 0);
            acc[1][1] = __builtin_amdgcn_mfma_f32_16x16x32_bf16(a1, b1, acc[1][1], 0, 0, 0);
        }
        #pragma unroll
        for (int m = 0; m < 2; ++m) {
            #pragma unroll
            for (int n = 0; n < 2; ++n) {
                int col = (nt0 + n) * 16 + lr;
                float c = cst[col];
                #pragma unroll
                for (int r = 0; r < 4; ++r) {
                    int row = m * 16 + lq * 4 + r;
                    Ha[row * LDA + col] = f2bf(softplus_fast(acc[m][n][r] + c));
                }
            }
        }
    }
    __syncthreads();

    // ================= G1: h1 = softplus(h0 @ P1 + cst1) =================
    {
        floatx4 acc[2][2];
        acc[0][0] = zero; acc[0][1] = zero; acc[1][0] = zero; acc[1][1] = zero;
        const int nt0 = ne * 2;
        #pragma unroll
        for (int kt = 0; kt < 8; ++kt) {
            short8 a0 = *(const short8*)&Ha[lr * LDA + kt * 32 + lq * 8];
            short8 a1 = *(const short8*)&Ha[(16 + lr) * LDA + kt * 32 + lq * 8];
            short8 b0 = *(const short8*)&wsp[P1_OFF + ((nt0 + 0) * 8 + kt) * 512 + l * 8];
            short8 b1 = *(const short8*)&wsp[P1_OFF + ((nt0 + 1) * 8 + kt) * 512 + l * 8];
            acc[0][0] = __builtin_amdgcn_mfma_f32_16x16x32_bf16(a0, b0, acc[0][0], 0, 0, 0);
            acc[0][1] = __builtin_amdgcn_mfma_f32_16x16x32_bf16(a0, b1, acc[0][1], 0, 0, 0);
            acc[1][0] = __builtin_amdgcn_mfma_f32_16x16x32_bf16(a1, b0, acc[1][0], 0, 0, 0);
            acc[1][1] = __builtin_amdgcn_mfma_f32_16x16x32_bf16(a1, b1, acc[1][1], 0, 0, 0);
        }
        #pragma unroll
        for (int m = 0; m < 2; ++m) {
            #pragma unroll
            for (int n = 0; n < 2; ++n) {
                int col = (nt0 + n) * 16 + lr;
                float c = cst[256 + col];
                #pragma unroll
                for (int r = 0; r < 4; ++r) {
                    int row = m * 16 + lq * 4 + r;
                    Hb[row * LDA + col] = f2bf(softplus_fast(acc[m][n][r] + c));
                }
            }
        }
    }
    __syncthreads();

    // ================= G2: dx = h1 @ P2 + cst2 -> out[:, :64] =================
    {
        floatx4 a0 = zero;
        #pragma unroll
        for (int kt = 0; kt < 8; ++kt) {
            short8 a = *(const short8*)&Hb[(mt * 16 + lr) * LDA + kt * 32 + lq * 8];
            short8 b = *(const short8*)&wsp[P2_OFF + (nq * 8 + kt) * 512 + l * 8];
            a0 = __builtin_amdgcn_mfma_f32_16x16x32_bf16(a, b, a0, 0, 0, 0);
        }
        int col = nq * 16 + lr;
        float c = cst[512 + col];
        #pragma unroll
        for (int r = 0; r < 4; ++r) {
            int row = mt * 16 + lq * 4 + r;
            out[(rowbase + row) * 65 + col] = a0[r] + c;
        }
    }
    __syncthreads();   // G2's Hb reads must finish before G3 overwrites Hb

    // ========= G3: g2 = e @ P3;  p1 = g2 * (1-exp(-h1)) -> Hb IN PLACE =========
    {
        floatx4 acc[2][2];
        acc[0][0] = zero; acc[0][1] = zero; acc[1][0] = zero; acc[1][1] = zero;
        const int nt0 = ne * 2;
        #pragma unroll
        for (int kt = 0; kt < 2; ++kt) {
            short8 a0 = *(const short8*)&Ae[lr * LDZ + kt * 32 + lq * 8];
            short8 a1 = *(const short8*)&Ae[(16 + lr) * LDZ + kt * 32 + lq * 8];
            short8 b0 = *(const short8*)&wsp[P3_OFF + ((nt0 + 0) * 2 + kt) * 512 + l * 8];
            short8 b1 = *(const short8*)&wsp[P3_OFF + ((nt0 + 1) * 2 + kt) * 512 + l * 8];
            acc[0][0] = __builtin_amdgcn_mfma_f32_16x16x32_bf16(a0, b0, acc[0][0], 0, 0, 0);
            acc[0][1] = __builtin_amdgcn_mfma_f32_16x16x32_bf16(a0, b1, acc[0][1], 0, 0, 0);
            acc[1][0] = __builtin_amdgcn_mfma_f32_16x16x32_bf16(a1, b0, acc[1][0], 0, 0, 0);
            acc[1][1] = __builtin_amdgcn_mfma_f32_16x16x32_bf16(a1, b1, acc[1][1], 0, 0, 0);
        }
        #pragma unroll
        for (int m = 0; m < 2; ++m) {
            #pragma unroll
            for (int n = 0; n < 2; ++n) {
                int col = (nt0 + n) * 16 + lr;
                #pragma unroll
                for (int r = 0; r < 4; ++r) {
                    int row = m * 16 + lq * 4 + r;
                    float g  = acc[m][n][r];
                    float ex = __expf(-bf2f(Hb[row * LDA + col]));
                    Hb[row * LDA + col] = f2bf(fmaf(-g, ex, g));   // g*(1-exp(-h1))
                }
            }
        }
    }
    __syncthreads();

    // ========= G4: g1 = p1 @ P4;  p0 = g1 * (1-exp(-h0)) -> Ha IN PLACE =========
    {
        floatx4 acc[2][2];
        acc[0][0] = zero; acc[0][1] = zero; acc[1][0] = zero; acc[1][1] = zero;
        const int nt0 = ne * 2;
        #pragma unroll
        for (int kt = 0; kt < 8; ++kt) {
            short8 a0 = *(const short8*)&Hb[lr * LDA + kt * 32 + lq * 8];
            short8 a1 = *(const short8*)&Hb[(16 + lr) * LDA + kt * 32 + lq * 8];
            short8 b0 = *(const short8*)&wsp[P4_OFF + ((nt0 + 0) * 8 + kt) * 512 + l * 8];
            short8 b1 = *(const short8*)&wsp[P4_OFF + ((nt0 + 1) * 8 + kt) * 512 + l * 8];
            acc[0][0] = __builtin_amdgcn_mfma_f32_16x16x32_bf16(a0, b0, acc[0][0], 0, 0, 0);
            acc[0][1] = __builtin_amdgcn_mfma_f32_16x16x32_bf16(a0, b1, acc[0][1], 0, 0, 0);
            acc[1][0] = __builtin_amdgcn_mfma_f32_16x16x32_bf16(a1, b0, acc[1][0], 0, 0, 0);
            acc[1][1] = __builtin_amdgcn_mfma_f32_16x16x32_bf16(a1, b1, acc[1][1], 0, 0, 0);
        }
        #pragma unroll
        for (int m = 0; m < 2; ++m) {
            #pragma unroll
            for (int n = 0; n < 2; ++n) {
                int col = (nt0 + n) * 16 + lr;
                #pragma unroll
                for (int r = 0; r < 4; ++r) {
                    int row = m * 16 + lq * 4 + r;
                    float g  = acc[m][n][r];
                    float ex = __expf(-bf2f(Ha[row * LDA + col]));
                    Ha[row * LDA + col] = f2bf(fmaf(-g, ex, g));   // g*(1-exp(-h0))
                }
            }
        }
    }
    __syncthreads();

    // ====== G5: g0 = p0 @ P5;  div = sum(g0 * e);  out[:,64] = -div ======
    {
        floatx4 a0 = zero;
        #pragma unroll
        for (int kt = 0; kt < 8; ++kt) {
            short8 a = *(const short8*)&Ha[(mt * 16 + lr) * LDA + kt * 32 + lq * 8];
            short8 b = *(const short8*)&wsp[P5_OFF + (nq * 8 + kt) * 512 + l * 8];
            a0 = __builtin_amdgcn_mfma_f32_16x16x32_bf16(a, b, a0, 0, 0, 0);
        }
        int col = nq * 16 + lr;
        #pragma unroll
        for (int r = 0; r < 4; ++r) {
            int row = mt * 16 + lq * 4 + r;
            float v = a0[r] * e[(rowbase + row) * 64 + col];
            #pragma unroll
            for (int m = 1; m < 16; m <<= 1) v += __shfl_xor(v, m, 64);
            if (lr == 0) divp[nq][row] = v;
        }
    }
    __syncthreads();
    if (tid < RB)
        out[(rowbase + tid) * 65 + 64] =
            -(divp[0][tid] + divp[1][tid] + divp[2][tid] + divp[3][tid]);
}

// ---------------- fp32 vector fallback (used only if ws_size too small) ----------------
#define FNT 256
__global__ __launch_bounds__(FNT, 2)
void ode_fallback(const float* __restrict__ tptr,
                  const float* __restrict__ y, const float* __restrict__ e,
                  const float* __restrict__ W0, const float* __restrict__ b0,
                  const float* __restrict__ W1, const float* __restrict__ b1,
                  const float* __restrict__ W2, const float* __restrict__ b2,
                  float* __restrict__ out)
{
    __shared__ float H0[RB * 257];
    __shared__ float H1[RB * 257];
    __shared__ float ZE[RB * 68];

    const int tid = threadIdx.x;
    const int rowbase = blockIdx.x * RB;
    const float tval = tptr[0];
    const int cg = tid & 31, rg = tid >> 5;
    const int cg2 = tid & 15, rg2 = tid >> 4;

    {
        const int d = tid & 63, r0 = tid >> 6;
        for (int r = r0; r < RB; r += FNT / 64)
            ZE[r * 68 + d] = y[(rowbase + r) * 65 + d];
    }
    __syncthreads();

    float acc[4][8];
    float acc2[2][4];

    for (int i = 0; i < 4; ++i) for (int j = 0; j < 8; ++j) acc[i][j] = 0.0f;
    for (int s = 0; s < 64; ++s) {
        float b[8];
        for (int j = 0; j < 8; ++j) b[j] = W0[(cg * 8 + j) * 65 + 1 + s];
        float a[4];
        for (int i = 0; i < 4; ++i) a[i] = ZE[(rg * 4 + i) * 68 + s];
        for (int i = 0; i < 4; ++i) for (int j = 0; j < 8; ++j)
            acc[i][j] = fmaf(a[i], b[j], acc[i][j]);
    }
    for (int i = 0; i < 4; ++i) for (int j = 0; j < 8; ++j) {
        int n = cg * 8 + j;
        H0[(rg * 4 + i) * 257 + n] = softplus_fast(acc[i][j] + tval * W0[n * 65] + b0[n]);
    }
    __syncthreads();

    for (int idx = tid; idx < RB * 16; idx += FNT) {
        int r = idx >> 4, c = idx & 15;
        *(float4*)(&ZE[r * 68 + c * 4]) = *(const float4*)(e + (rowbase + r) * 64 + c * 4);
    }

    for (int i = 0; i < 4; ++i) for (int j = 0; j < 8; ++j) acc[i][j] = 0.0f;
    for (int s = 0; s < 256; ++s) {
        float b[8];
        for (int j = 0; j < 8; ++j) b[j] = W1[(cg * 8 + j) * 257 + 1 + s];
        float a[4];
        for (int i = 0; i < 4; ++i) a[i] = H0[(rg * 4 + i) * 257 + s];
        for (int i = 0; i < 4; ++i) for (int j = 0; j < 8; ++j)
            acc[i][j] = fmaf(a[i], b[j], acc[i][j]);
    }
    for (int i = 0; i < 4; ++i) for (int j = 0; j < 8; ++j) {
        int n = cg * 8 + j;
        H1[(rg * 4 + i) * 257 + n] = softplus_fast(acc[i][j] + tval * W1[n * 257] + b1[n]);
    }
    __syncthreads();

    for (int i = 0; i < 2; ++i) for (int j = 0; j < 4; ++j) acc2[i][j] = 0.0f;
    for (int s = 0; s < 256; ++s) {
        float b[4];
        for (int j = 0; j < 4; ++j) b[j] = W2[(cg2 * 4 + j) * 257 + 1 + s];
        float a[2];
        for (int i = 0; i < 2; ++i) a[i] = H1[(rg2 * 2 + i) * 257 + s];
        for (int i = 0; i < 2; ++i) for (int j = 0; j < 4; ++j)
            acc2[i][j] = fmaf(a[i], b[j], acc2[i][j]);
    }
    for (int i = 0; i < 2; ++i) for (int j = 0; j < 4; ++j) {
        int n = cg2 * 4 + j;
        out[(rowbase + rg2 * 2 + i) * 65 + n] = acc2[i][j] + tval * W2[n * 257] + b2[n];
    }
    __syncthreads();

    for (int i = 0; i < 4; ++i) for (int j = 0; j < 8; ++j) acc[i][j] = 0.0f;
    for (int s = 0; s < 64; ++s) {
        float b[8];
        for (int j = 0; j < 8; ++j) b[j] = W2[s * 257 + 1 + cg * 8 + j];
        float a[4];
        for (int i = 0; i < 4; ++i) a[i] = ZE[(rg * 4 + i) * 68 + s];
        for (int i = 0; i < 4; ++i) for (int j = 0; j < 8; ++j)
            acc[i][j] = fmaf(a[i], b[j], acc[i][j]);
    }
    for (int i = 0; i < 4; ++i) for (int j = 0; j < 8; ++j) {
        int r = rg * 4 + i, n = cg * 8 + j;
        float h = H1[r * 257 + n];
        H1[r * 257 + n] = acc[i][j] * (1.0f - __expf(-h));
    }
    __syncthreads();

    for (int i = 0; i < 4; ++i) for (int j = 0; j < 8; ++j) acc[i][j] = 0.0f;
    for (int s = 0; s < 256; ++s) {
        float b[8];
        for (int j = 0; j < 8; ++j) b[j] = W1[s * 257 + 1 + cg * 8 + j];
        float a[4];
        for (int i = 0; i < 4; ++i) a[i] = H1[(rg * 4 + i) * 257 + s];
        for (int i = 0; i < 4; ++i) for (int j = 0; j < 8; ++j)
            acc[i][j] = fmaf(a[i], b[j], acc[i][j]);
    }
    for (int i = 0; i < 4; ++i) for (int j = 0; j < 8; ++j) {
        int r = rg * 4 + i, n = cg * 8 + j;
        float h = H0[r * 257 + n];
        H0[r * 257 + n] = acc[i][j] * (1.0f - __expf(-h));
    }
    __syncthreads();

    for (int i = 0; i < 2; ++i) for (int j = 0; j < 4; ++j) acc2[i][j] = 0.0f;
    for (int s = 0; s < 256; ++s) {
        float b[4];
        for (int j = 0; j < 4; ++j) b[j] = W0[s * 65 + 1 + cg2 * 4 + j];
        float a[2];
        for (int i = 0; i < 2; ++i) a[i] = H0[(rg2 * 2 + i) * 257 + s];
        for (int i = 0; i < 2; ++i) for (int j = 0; j < 4; ++j)
            acc2[i][j] = fmaf(a[i], b[j], acc2[i][j]);
    }
    float pA = 0.0f, pB = 0.0f;
    for (int j = 0; j < 4; ++j) {
        int n = cg2 * 4 + j;
        pA = fmaf(acc2[0][j], ZE[(rg2 * 2 + 0) * 68 + n], pA);
        pB = fmaf(acc2[1][j], ZE[(rg2 * 2 + 1) * 68 + n], pB);
    }
    for (int off = 8; off > 0; off >>= 1) {
        pA += __shfl_down(pA, off, 16);
        pB += __shfl_down(pB, off, 16);
    }
    if (cg2 == 0) {
        out[(rowbase + rg2 * 2 + 0) * 65 + 64] = -pA;
        out[(rowbase + rg2 * 2 + 1) * 65 + 64] = -pB;
    }
}

extern "C" void kernel_launch(void* const* d_in, const int* in_sizes, int n_in,
                              void* d_out, int out_size, void* d_ws, size_t ws_size,
                              hipStream_t stream)
{
    const float* t  = (const float*)d_in[0];
    const float* y  = (const float*)d_in[1];
    const float* e  = (const float*)d_in[2];
    const float* W0 = (const float*)d_in[3];
    const float* b0 = (const float*)d_in[4];
    const float* W1 = (const float*)d_in[5];
    const float* b1 = (const float*)d_in[6];
    const float* W2 = (const float*)d_in[7];
    const float* b2 = (const float*)d_in[8];
    float* out = (float*)d_out;

    const int B = in_sizes[1] / 65;

    if (ws_size >= (size_t)WS_BYTES) {
        prep_pack<<<(PACK_ELEMS + 576 + 255) / 256, 256, 0, stream>>>(
            t, W0, b0, W1, b1, W2, b2, (short*)d_ws);
        ode_mfma<<<B / RB, NT, 0, stream>>>(y, e, (const short*)d_ws, out);
    } else {
        ode_fallback<<<B / RB, FNT, 0, stream>>>(t, y, e, W0, b0, W1, b1, W2, b2, out);
    }
}